// Round 8
// baseline (252.648 us; speedup 1.0000x reference)
//
#include <hip/hip_runtime.h>

#define B_SZ 8192
#define C_DIM 128
#define D_DIM 512
#define PAIR_CAP 65536

typedef __bf16 bf16x8 __attribute__((ext_vector_type(8)));
typedef float  f32x4  __attribute__((ext_vector_type(4)));

// RNE float -> bf16 (inputs are finite positive probabilities; no NaN path)
__device__ inline unsigned int f2bf(float f) {
    unsigned int u = __builtin_bit_cast(unsigned int, f);
    u += 0x7FFFu + ((u >> 16) & 1u);
    return u >> 16;
}

// ---------------------------------------------------------------------------
// Kernel 0 (fused prep): blocks [0,1024) convert P,Q fp32->bf16 into ws;
// blocks [1024,3072) compute ordered top-5 keys of feat rows (one wave/row,
// 5 rounds of wave-argmax, lower-index tiebreak). Block 0 zeroes acc/cnt.
// ---------------------------------------------------------------------------
__global__ __launch_bounds__(256) void prep_kernel(
    const float* __restrict__ feat,
    const float* __restrict__ P, const float* __restrict__ Q,
    unsigned short* __restrict__ bfP, unsigned short* __restrict__ bfQ,
    unsigned long long* __restrict__ keys,
    float* __restrict__ acc, int* __restrict__ cnt)
{
    if (blockIdx.x == 0 && threadIdx.x == 0) { *acc = 0.0f; *cnt = 0; }

    if (blockIdx.x < 1024) {
        const int half = (B_SZ * C_DIM) / 8;          // 131072 vec8 per array
        int idx = blockIdx.x * 256 + threadIdx.x;
        const float* src = P; unsigned short* dst = bfP;
        if (idx >= half) { idx -= half; src = Q; dst = bfQ; }
        float4 a = *reinterpret_cast<const float4*>(src + (size_t)idx * 8);
        float4 b = *reinterpret_cast<const float4*>(src + (size_t)idx * 8 + 4);
        uint4 w;
        w.x = f2bf(a.x) | (f2bf(a.y) << 16);
        w.y = f2bf(a.z) | (f2bf(a.w) << 16);
        w.z = f2bf(b.x) | (f2bf(b.y) << 16);
        w.w = f2bf(b.z) | (f2bf(b.w) << 16);
        *reinterpret_cast<uint4*>(dst + (size_t)idx * 8) = w;
        return;
    }

    const int lane = threadIdx.x & 63;
    const int wv   = threadIdx.x >> 6;
    const int row  = (blockIdx.x - 1024) * 4 + wv;
    const float* f = feat + (size_t)row * D_DIM;

    const int base = lane * 8;
    float v[8];
    float4 a = *reinterpret_cast<const float4*>(f + base);
    float4 b = *reinterpret_cast<const float4*>(f + base + 4);
    v[0]=a.x; v[1]=a.y; v[2]=a.z; v[3]=a.w;
    v[4]=b.x; v[5]=b.y; v[6]=b.z; v[7]=b.w;

    unsigned sel = 0;
    unsigned long long key = 0;
    for (int k = 0; k < 5; ++k) {
        float best = -3.0e38f;
        int  bidx = 0x7fffffff;
        #pragma unroll
        for (int j = 0; j < 8; ++j) {
            if (!((sel >> j) & 1u)) {
                float val = v[j];
                int   idx = base + j;
                if (val > best || (val == best && idx < bidx)) { best = val; bidx = idx; }
            }
        }
        #pragma unroll
        for (int off = 32; off > 0; off >>= 1) {
            float ov = __shfl_xor(best, off);
            int   oi = __shfl_xor(bidx, off);
            if (ov > best || (ov == best && oi < bidx)) { best = ov; bidx = oi; }
        }
        key |= (unsigned long long)(unsigned)bidx << (10 * k);
        if (bidx >= base && bidx < base + 8) sel |= 1u << (bidx - base);
    }
    if (lane == 0) keys[row] = key;
}

// ---------------------------------------------------------------------------
// Kernel 1 (fused): blocks [0,4096): GEMM tile + BCE-log-product epilogue.
//   128x128 tile / 256 threads (2x2 waves, each 64x64 out), full K=128 in
//   64 KB LDS -> 2 blocks/CU co-resident: one block's global_load_lds stage
//   overlaps the other's MFMA compute (the R7 256²-tile ran 1 block/CU with
//   the stage stall fully exposed).
//   Swizzle (verified R3-R7): granule g: rr=g>>4, s=g&15, src chunk s^(rr&7);
//   b128 reads at rr*128 + ((c*8)^((rr&7)*8)) -> 2-way bank (free).
//   Diagonal blocks (bi==bj) use x=p on i==j, else x=1-p. One log2/thread.
// blocks [4096,5120): pair_find for OFF-DIAGONAL key duplicates (expected 0).
// ---------------------------------------------------------------------------
__global__ __launch_bounds__(256) void gemm_pf_kernel(
    const unsigned short* __restrict__ bfP,
    const unsigned short* __restrict__ bfQ,
    const unsigned long long* __restrict__ keys,
    unsigned int* __restrict__ pairs, int* __restrict__ cnt,
    float* __restrict__ acc)
{
    __shared__ unsigned short As[128 * 128];   // 32 KB
    __shared__ unsigned short Bs[128 * 128];   // 32 KB

    const int tid = threadIdx.x;

    if (blockIdx.x >= 4096) {
        // ---- pair-find tail blocks ----
        unsigned long long* kjs = reinterpret_cast<unsigned long long*>(As);
        const int b = blockIdx.x - 4096;
        const int ibase = (b >> 5) * 256;
        const int jbase = (b & 31) * 256;
        kjs[tid] = keys[jbase + tid];
        __syncthreads();
        const int i = ibase + tid;
        const unsigned long long ki = keys[i];
        #pragma unroll
        for (int batch = 0; batch < 32; ++batch) {
            unsigned long long kk[8];
            #pragma unroll
            for (int x = 0; x < 8; ++x) kk[x] = kjs[batch * 8 + x];
            #pragma unroll
            for (int x = 0; x < 8; ++x) {
                const int j = jbase + batch * 8 + x;
                if (kk[x] == ki && j != i) {
                    int slot = atomicAdd(cnt, 1);
                    if (slot < PAIR_CAP)
                        pairs[slot] = ((unsigned)i << 13) | (unsigned)j;
                }
            }
        }
        return;
    }

    const int bi = blockIdx.x & 63;
    const int bj = blockIdx.x >> 6;
    const int row0 = bi << 7, col0 = bj << 7;

    // ---- stage: async global->LDS, 16B/lane, 8 rounds per array ----
    #pragma unroll
    for (int it = 0; it < 8; ++it) {
        const int g  = it * 256 + tid;       // granule (16B) index, [0,2048)
        const int rr = g >> 4;
        const int s  = g & 15;
        const int cw = s ^ (rr & 7);         // pre-swizzled source chunk
        const unsigned short* sA = bfP + (size_t)(row0 + rr) * C_DIM + cw * 8;
        const unsigned short* sB = bfQ + (size_t)(col0 + rr) * C_DIM + cw * 8;
        __builtin_amdgcn_global_load_lds(
            (const __attribute__((address_space(1))) void*)sA,
            (__attribute__((address_space(3))) void*)(As + g * 8), 16, 0, 0);
        __builtin_amdgcn_global_load_lds(
            (const __attribute__((address_space(1))) void*)sB,
            (__attribute__((address_space(3))) void*)(Bs + g * 8), 16, 0, 0);
    }
    __syncthreads();

    // ---- compute: 4 waves (2x2), each 64x64 output; K=128, 4 MFMA steps ----
    const int l  = tid & 63;
    const int wv = tid >> 6;
    const int wm = wv >> 1, wn = wv & 1;
    const int g8 = l >> 4, q = l & 15;

    f32x4 accf[4][4];
    #pragma unroll
    for (int mi = 0; mi < 4; ++mi)
        #pragma unroll
        for (int ni = 0; ni < 4; ++ni) accf[mi][ni] = (f32x4){0.f, 0.f, 0.f, 0.f};

    #pragma unroll
    for (int ks = 0; ks < 4; ++ks) {
        bf16x8 af[4], bfr[4];
        #pragma unroll
        for (int mi = 0; mi < 4; ++mi) {
            const int rr = wm * 64 + mi * 16 + q;
            af[mi] = *reinterpret_cast<const bf16x8*>(
                &As[rr * 128 + ((ks * 32 + g8 * 8) ^ ((rr & 7) << 3))]);
        }
        #pragma unroll
        for (int ni = 0; ni < 4; ++ni) {
            const int rr = wn * 64 + ni * 16 + q;
            bfr[ni] = *reinterpret_cast<const bf16x8*>(
                &Bs[rr * 128 + ((ks * 32 + g8 * 8) ^ ((rr & 7) << 3))]);
        }
        #pragma unroll
        for (int mi = 0; mi < 4; ++mi)
            #pragma unroll
            for (int ni = 0; ni < 4; ++ni)
                accf[mi][ni] = __builtin_amdgcn_mfma_f32_16x16x32_bf16(
                    af[mi], bfr[ni], accf[mi][ni], 0, 0, 0);
    }

    // ---- epilogue: product of 64 factors, one log2 per thread ----
    float pr[4] = {1.0f, 1.0f, 1.0f, 1.0f};
    if (bi == bj) {
        #pragma unroll
        for (int mi = 0; mi < 4; ++mi) {
            #pragma unroll
            for (int ni = 0; ni < 4; ++ni) {
                const int lj = wn * 64 + ni * 16 + q;
                #pragma unroll
                for (int r = 0; r < 4; ++r) {
                    const float p = accf[mi][ni][r];
                    const int li = wm * 64 + mi * 16 + g8 * 4 + r;
                    pr[r] *= (li == lj) ? p : (1.0f - p);
                }
            }
        }
    } else {
        #pragma unroll
        for (int mi = 0; mi < 4; ++mi)
            #pragma unroll
            for (int ni = 0; ni < 4; ++ni)
                #pragma unroll
                for (int r = 0; r < 4; ++r)
                    pr[r] *= 1.0f - accf[mi][ni][r];
    }
    float lsum = __log2f((pr[0] * pr[1]) * (pr[2] * pr[3]));

    #pragma unroll
    for (int off = 32; off > 0; off >>= 1) lsum += __shfl_xor(lsum, off);
    if (l == 0)
        atomicAdd(acc, lsum * 0.69314718055994531f);   // fire-and-forget
}

// ---------------------------------------------------------------------------
// Kernel 2 (fused): duplicate-pair correction (expected 0 pairs) + finalize.
// Single block; waves grid-stride the pair list (fp32 dot, butterfly reduce),
// then thread 0 combines with the global accumulator and writes the loss.
// ---------------------------------------------------------------------------
__global__ __launch_bounds__(256) void fix_final_kernel(
    const unsigned int* __restrict__ pairs, const int* __restrict__ cnt,
    const float* __restrict__ P, const float* __restrict__ Q,
    const float* __restrict__ acc, float* __restrict__ out)
{
    __shared__ float wsum[4];
    const int lane = threadIdx.x & 63;
    const int w    = threadIdx.x >> 6;
    const int count = min(*cnt, PAIR_CAP);

    float lsum = 0.0f;
    for (int p = w; p < count; p += 4) {
        const unsigned code = pairs[p];
        const int i = code >> 13;
        const int j = code & 8191;
        float2 a = *reinterpret_cast<const float2*>(P + (size_t)i * C_DIM + lane * 2);
        float2 b = *reinterpret_cast<const float2*>(Q + (size_t)j * C_DIM + lane * 2);
        float s = fmaf(a.x, b.x, a.y * b.y);
        #pragma unroll
        for (int off = 32; off > 0; off >>= 1) s += __shfl_xor(s, off);
        if (lane == 0)
            lsum += fmaxf(__logf(s), -100.0f) - __logf(1.0f - s);
    }
    if (lane == 0) wsum[w] = lsum;
    __syncthreads();
    if (threadIdx.x == 0) {
        float total = acc[0] + wsum[0] + wsum[1] + wsum[2] + wsum[3];
        out[0] = -total / (float)((long long)B_SZ * (long long)B_SZ);
    }
}

extern "C" void kernel_launch(void* const* d_in, const int* in_sizes, int n_in,
                              void* d_out, int out_size, void* d_ws, size_t ws_size,
                              hipStream_t stream)
{
    const float* feat = (const float*)d_in[0];   // unlabel_feat     (8192, 512)
    const float* prob = (const float*)d_in[1];   // unlabel_prob     (8192, 128)
    const float* rot  = (const float*)d_in[2];   // rot_unlabel_prob (8192, 128)
    float* out = (float*)d_out;

    char* ws = (char*)d_ws;
    unsigned long long* keys = (unsigned long long*)ws;             // 64 KB
    float* acc = (float*)(ws + 65536);
    int*   cnt = (int*)(ws + 65544);
    unsigned short* bfP = (unsigned short*)(ws + 66560);            // 2 MB
    unsigned short* bfQ = bfP + (size_t)B_SZ * C_DIM;               // 2 MB
    unsigned int* pairs = (unsigned int*)(ws + 66560 + 4 * 1024 * 1024); // 256 KB

    prep_kernel<<<3072, 256, 0, stream>>>(feat, prob, rot, bfP, bfQ, keys, acc, cnt);
    gemm_pf_kernel<<<4096 + 1024, 256, 0, stream>>>(bfP, bfQ, keys, pairs, cnt, acc);
    fix_final_kernel<<<1, 256, 0, stream>>>(pairs, cnt, prob, rot, acc, out);
}

// Round 9
// 66.418 us; speedup vs baseline: 3.8039x; 3.8039x over previous
//
#include <hip/hip_runtime.h>

#define B_SZ 8192
#define C_DIM 128
#define D_DIM 512
#define PAIR_CAP 65536
#define NBINS 256
#define BIN_STRIDE 16   // floats; 64 B -> one cache line per bin

typedef __bf16 bf16x8 __attribute__((ext_vector_type(8)));
typedef float  f32x4  __attribute__((ext_vector_type(4)));

// RNE float -> bf16 (inputs are finite positive probabilities; no NaN path)
__device__ inline unsigned int f2bf(float f) {
    unsigned int u = __builtin_bit_cast(unsigned int, f);
    u += 0x7FFFu + ((u >> 16) & 1u);
    return u >> 16;
}

// ---------------------------------------------------------------------------
// Kernel 0 (fused prep): blocks [0,1024) convert P,Q fp32->bf16 into ws;
// blocks [1024,3072) compute ordered top-5 keys of feat rows (one wave/row,
// 5 rounds of wave-argmax, lower-index tiebreak).
// Block 0: threads 0..255 zero the 256 accumulator bins; thread 0 zeroes cnt.
// ---------------------------------------------------------------------------
__global__ __launch_bounds__(256) void prep_kernel(
    const float* __restrict__ feat,
    const float* __restrict__ P, const float* __restrict__ Q,
    unsigned short* __restrict__ bfP, unsigned short* __restrict__ bfQ,
    unsigned long long* __restrict__ keys,
    float* __restrict__ accbins, int* __restrict__ cnt)
{
    if (blockIdx.x == 0) {
        accbins[threadIdx.x * BIN_STRIDE] = 0.0f;
        if (threadIdx.x == 0) *cnt = 0;
    }

    if (blockIdx.x < 1024) {
        const int half = (B_SZ * C_DIM) / 8;          // 131072 vec8 per array
        int idx = blockIdx.x * 256 + threadIdx.x;
        const float* src = P; unsigned short* dst = bfP;
        if (idx >= half) { idx -= half; src = Q; dst = bfQ; }
        float4 a = *reinterpret_cast<const float4*>(src + (size_t)idx * 8);
        float4 b = *reinterpret_cast<const float4*>(src + (size_t)idx * 8 + 4);
        uint4 w;
        w.x = f2bf(a.x) | (f2bf(a.y) << 16);
        w.y = f2bf(a.z) | (f2bf(a.w) << 16);
        w.z = f2bf(b.x) | (f2bf(b.y) << 16);
        w.w = f2bf(b.z) | (f2bf(b.w) << 16);
        *reinterpret_cast<uint4*>(dst + (size_t)idx * 8) = w;
        return;
    }

    const int lane = threadIdx.x & 63;
    const int wv   = threadIdx.x >> 6;
    const int row  = (blockIdx.x - 1024) * 4 + wv;
    const float* f = feat + (size_t)row * D_DIM;

    const int base = lane * 8;
    float v[8];
    float4 a = *reinterpret_cast<const float4*>(f + base);
    float4 b = *reinterpret_cast<const float4*>(f + base + 4);
    v[0]=a.x; v[1]=a.y; v[2]=a.z; v[3]=a.w;
    v[4]=b.x; v[5]=b.y; v[6]=b.z; v[7]=b.w;

    unsigned sel = 0;
    unsigned long long key = 0;
    for (int k = 0; k < 5; ++k) {
        float best = -3.0e38f;
        int  bidx = 0x7fffffff;
        #pragma unroll
        for (int j = 0; j < 8; ++j) {
            if (!((sel >> j) & 1u)) {
                float val = v[j];
                int   idx = base + j;
                if (val > best || (val == best && idx < bidx)) { best = val; bidx = idx; }
            }
        }
        #pragma unroll
        for (int off = 32; off > 0; off >>= 1) {
            float ov = __shfl_xor(best, off);
            int   oi = __shfl_xor(bidx, off);
            if (ov > best || (ov == best && oi < bidx)) { best = ov; bidx = oi; }
        }
        key |= (unsigned long long)(unsigned)bidx << (10 * k);
        if (bidx >= base && bidx < base + 8) sel |= 1u << (bidx - base);
    }
    if (lane == 0) keys[row] = key;
}

// ---------------------------------------------------------------------------
// Kernel 1 (fused): blocks [0,4096): GEMM tile + BCE-log-product epilogue.
//   128x128 tile / 256 threads (2x2 waves, each 64x64 out), K=128 in 64 KB
//   LDS -> 2 blocks/CU so one block's stage overlaps the other's MFMA.
//   Epilogue: per-thread product of 64 factors, ONE log2, per-BLOCK LDS
//   reduction, ONE atomicAdd into a cache-line-padded bin (blockIdx&255).
//   (R8 lesson: 16384 same-line atomics serialize at ~12 ns each = 197 us.)
// blocks [4096,5120): pair_find for OFF-DIAGONAL key duplicates (expected 0).
// ---------------------------------------------------------------------------
__global__ __launch_bounds__(256) void gemm_pf_kernel(
    const unsigned short* __restrict__ bfP,
    const unsigned short* __restrict__ bfQ,
    const unsigned long long* __restrict__ keys,
    unsigned int* __restrict__ pairs, int* __restrict__ cnt,
    float* __restrict__ accbins)
{
    __shared__ unsigned short As[128 * 128];   // 32 KB
    __shared__ unsigned short Bs[128 * 128];   // 32 KB
    __shared__ float wsum[4];

    const int tid = threadIdx.x;

    if (blockIdx.x >= 4096) {
        // ---- pair-find tail blocks ----
        unsigned long long* kjs = reinterpret_cast<unsigned long long*>(As);
        const int b = blockIdx.x - 4096;
        const int ibase = (b >> 5) * 256;
        const int jbase = (b & 31) * 256;
        kjs[tid] = keys[jbase + tid];
        __syncthreads();
        const int i = ibase + tid;
        const unsigned long long ki = keys[i];
        #pragma unroll
        for (int batch = 0; batch < 32; ++batch) {
            unsigned long long kk[8];
            #pragma unroll
            for (int x = 0; x < 8; ++x) kk[x] = kjs[batch * 8 + x];
            #pragma unroll
            for (int x = 0; x < 8; ++x) {
                const int j = jbase + batch * 8 + x;
                if (kk[x] == ki && j != i) {
                    int slot = atomicAdd(cnt, 1);
                    if (slot < PAIR_CAP)
                        pairs[slot] = ((unsigned)i << 13) | (unsigned)j;
                }
            }
        }
        return;
    }

    const int bi = blockIdx.x & 63;
    const int bj = blockIdx.x >> 6;
    const int row0 = bi << 7, col0 = bj << 7;

    // ---- stage: async global->LDS, 16B/lane, 8 rounds per array ----
    #pragma unroll
    for (int it = 0; it < 8; ++it) {
        const int g  = it * 256 + tid;       // granule (16B) index, [0,2048)
        const int rr = g >> 4;
        const int s  = g & 15;
        const int cw = s ^ (rr & 7);         // pre-swizzled source chunk
        const unsigned short* sA = bfP + (size_t)(row0 + rr) * C_DIM + cw * 8;
        const unsigned short* sB = bfQ + (size_t)(col0 + rr) * C_DIM + cw * 8;
        __builtin_amdgcn_global_load_lds(
            (const __attribute__((address_space(1))) void*)sA,
            (__attribute__((address_space(3))) void*)(As + g * 8), 16, 0, 0);
        __builtin_amdgcn_global_load_lds(
            (const __attribute__((address_space(1))) void*)sB,
            (__attribute__((address_space(3))) void*)(Bs + g * 8), 16, 0, 0);
    }
    __syncthreads();

    // ---- compute: 4 waves (2x2), each 64x64 output; K=128, 4 MFMA steps ----
    const int l  = tid & 63;
    const int wv = tid >> 6;
    const int wm = wv >> 1, wn = wv & 1;
    const int g8 = l >> 4, q = l & 15;

    f32x4 accf[4][4];
    #pragma unroll
    for (int mi = 0; mi < 4; ++mi)
        #pragma unroll
        for (int ni = 0; ni < 4; ++ni) accf[mi][ni] = (f32x4){0.f, 0.f, 0.f, 0.f};

    #pragma unroll
    for (int ks = 0; ks < 4; ++ks) {
        bf16x8 af[4], bfr[4];
        #pragma unroll
        for (int mi = 0; mi < 4; ++mi) {
            const int rr = wm * 64 + mi * 16 + q;
            af[mi] = *reinterpret_cast<const bf16x8*>(
                &As[rr * 128 + ((ks * 32 + g8 * 8) ^ ((rr & 7) << 3))]);
        }
        #pragma unroll
        for (int ni = 0; ni < 4; ++ni) {
            const int rr = wn * 64 + ni * 16 + q;
            bfr[ni] = *reinterpret_cast<const bf16x8*>(
                &Bs[rr * 128 + ((ks * 32 + g8 * 8) ^ ((rr & 7) << 3))]);
        }
        #pragma unroll
        for (int mi = 0; mi < 4; ++mi)
            #pragma unroll
            for (int ni = 0; ni < 4; ++ni)
                accf[mi][ni] = __builtin_amdgcn_mfma_f32_16x16x32_bf16(
                    af[mi], bfr[ni], accf[mi][ni], 0, 0, 0);
    }

    // ---- epilogue: product of 64 factors, one log2 per thread ----
    float pr[4] = {1.0f, 1.0f, 1.0f, 1.0f};
    if (bi == bj) {
        #pragma unroll
        for (int mi = 0; mi < 4; ++mi) {
            #pragma unroll
            for (int ni = 0; ni < 4; ++ni) {
                const int lj = wn * 64 + ni * 16 + q;
                #pragma unroll
                for (int r = 0; r < 4; ++r) {
                    const float p = accf[mi][ni][r];
                    const int li = wm * 64 + mi * 16 + g8 * 4 + r;
                    pr[r] *= (li == lj) ? p : (1.0f - p);
                }
            }
        }
    } else {
        #pragma unroll
        for (int mi = 0; mi < 4; ++mi)
            #pragma unroll
            for (int ni = 0; ni < 4; ++ni)
                #pragma unroll
                for (int r = 0; r < 4; ++r)
                    pr[r] *= 1.0f - accf[mi][ni][r];
    }
    float lsum = __log2f((pr[0] * pr[1]) * (pr[2] * pr[3]));

    #pragma unroll
    for (int off = 32; off > 0; off >>= 1) lsum += __shfl_xor(lsum, off);
    if (l == 0) wsum[wv] = lsum;
    __syncthreads();
    if (tid == 0) {
        const float s = wsum[0] + wsum[1] + wsum[2] + wsum[3];
        atomicAdd(accbins + (blockIdx.x & (NBINS - 1)) * BIN_STRIDE,
                  s * 0.69314718055994531f);
    }
}

// ---------------------------------------------------------------------------
// Kernel 2 (fused): duplicate-pair correction (expected 0 pairs) + bin sum +
// finalize. Single block of 256 threads.
// ---------------------------------------------------------------------------
__global__ __launch_bounds__(256) void fix_final_kernel(
    const unsigned int* __restrict__ pairs, const int* __restrict__ cnt,
    const float* __restrict__ P, const float* __restrict__ Q,
    const float* __restrict__ accbins, float* __restrict__ out)
{
    __shared__ float wsum[4];
    __shared__ float bsum[4];
    const int lane = threadIdx.x & 63;
    const int w    = threadIdx.x >> 6;
    const int count = min(*cnt, PAIR_CAP);

    // pair corrections (one wave per pair, 4-wave stride)
    float lsum = 0.0f;
    for (int p = w; p < count; p += 4) {
        const unsigned code = pairs[p];
        const int i = code >> 13;
        const int j = code & 8191;
        float2 a = *reinterpret_cast<const float2*>(P + (size_t)i * C_DIM + lane * 2);
        float2 b = *reinterpret_cast<const float2*>(Q + (size_t)j * C_DIM + lane * 2);
        float s = fmaf(a.x, b.x, a.y * b.y);
        #pragma unroll
        for (int off = 32; off > 0; off >>= 1) s += __shfl_xor(s, off);
        if (lane == 0)
            lsum += fmaxf(__logf(s), -100.0f) - __logf(1.0f - s);
    }
    if (lane == 0) wsum[w] = lsum;

    // bin sum: thread t owns bin t
    float bv = accbins[threadIdx.x * BIN_STRIDE];
    #pragma unroll
    for (int off = 32; off > 0; off >>= 1) bv += __shfl_xor(bv, off);
    if (lane == 0) bsum[w] = bv;
    __syncthreads();

    if (threadIdx.x == 0) {
        float total = wsum[0] + wsum[1] + wsum[2] + wsum[3]
                    + bsum[0] + bsum[1] + bsum[2] + bsum[3];
        out[0] = -total / (float)((long long)B_SZ * (long long)B_SZ);
    }
}

extern "C" void kernel_launch(void* const* d_in, const int* in_sizes, int n_in,
                              void* d_out, int out_size, void* d_ws, size_t ws_size,
                              hipStream_t stream)
{
    const float* feat = (const float*)d_in[0];   // unlabel_feat     (8192, 512)
    const float* prob = (const float*)d_in[1];   // unlabel_prob     (8192, 128)
    const float* rot  = (const float*)d_in[2];   // rot_unlabel_prob (8192, 128)
    float* out = (float*)d_out;

    char* ws = (char*)d_ws;
    unsigned long long* keys = (unsigned long long*)ws;               // 64 KB
    int*   cnt     = (int*)(ws + 65536);
    float* accbins = (float*)(ws + 66560);                            // 16 KB
    unsigned short* bfP = (unsigned short*)(ws + 66560 + 16384);      // 2 MB
    unsigned short* bfQ = bfP + (size_t)B_SZ * C_DIM;                 // 2 MB
    unsigned int* pairs = (unsigned int*)(ws + 66560 + 16384 + 4 * 1024 * 1024);

    prep_kernel<<<3072, 256, 0, stream>>>(feat, prob, rot, bfP, bfQ, keys, accbins, cnt);
    gemm_pf_kernel<<<4096 + 1024, 256, 0, stream>>>(bfP, bfQ, keys, pairs, cnt, accbins);
    fix_final_kernel<<<1, 256, 0, stream>>>(pairs, cnt, prob, rot, accbins, out);
}

// Round 10
// 58.395 us; speedup vs baseline: 4.3265x; 1.1374x over previous
//
#include <hip/hip_runtime.h>

#define B_SZ 8192
#define C_DIM 128
#define D_DIM 512
#define PAIR_CAP 65536
#define NBINS 256
#define BIN_STRIDE 16   // floats; 64 B -> one cache line per bin
#define NT 16           // tiles per persistent gemm block

typedef __bf16 bf16x8 __attribute__((ext_vector_type(8)));
typedef float  f32x4  __attribute__((ext_vector_type(4)));

// RNE float -> bf16 (inputs are finite positive probabilities; no NaN path)
__device__ inline unsigned int f2bf(float f) {
    unsigned int u = __builtin_bit_cast(unsigned int, f);
    u += 0x7FFFu + ((u >> 16) & 1u);
    return u >> 16;
}

// ---------------------------------------------------------------------------
// Kernel 0 (fused prep): blocks [0,1024) convert P,Q fp32->bf16 into ws;
// blocks [1024,3072) compute ordered top-5 keys of feat rows (one wave/row,
// 5 rounds of wave-argmax, lower-index tiebreak).
// Block 0: threads zero the 256 accumulator bins; thread 0 zeroes cnt.
// ---------------------------------------------------------------------------
__global__ __launch_bounds__(256) void prep_kernel(
    const float* __restrict__ feat,
    const float* __restrict__ P, const float* __restrict__ Q,
    unsigned short* __restrict__ bfP, unsigned short* __restrict__ bfQ,
    unsigned long long* __restrict__ keys,
    float* __restrict__ accbins, int* __restrict__ cnt)
{
    if (blockIdx.x == 0) {
        accbins[threadIdx.x * BIN_STRIDE] = 0.0f;
        if (threadIdx.x == 0) *cnt = 0;
    }

    if (blockIdx.x < 1024) {
        const int half = (B_SZ * C_DIM) / 8;          // 131072 vec8 per array
        int idx = blockIdx.x * 256 + threadIdx.x;
        const float* src = P; unsigned short* dst = bfP;
        if (idx >= half) { idx -= half; src = Q; dst = bfQ; }
        float4 a = *reinterpret_cast<const float4*>(src + (size_t)idx * 8);
        float4 b = *reinterpret_cast<const float4*>(src + (size_t)idx * 8 + 4);
        uint4 w;
        w.x = f2bf(a.x) | (f2bf(a.y) << 16);
        w.y = f2bf(a.z) | (f2bf(a.w) << 16);
        w.z = f2bf(b.x) | (f2bf(b.y) << 16);
        w.w = f2bf(b.z) | (f2bf(b.w) << 16);
        *reinterpret_cast<uint4*>(dst + (size_t)idx * 8) = w;
        return;
    }

    const int lane = threadIdx.x & 63;
    const int wv   = threadIdx.x >> 6;
    const int row  = (blockIdx.x - 1024) * 4 + wv;
    const float* f = feat + (size_t)row * D_DIM;

    const int base = lane * 8;
    float v[8];
    float4 a = *reinterpret_cast<const float4*>(f + base);
    float4 b = *reinterpret_cast<const float4*>(f + base + 4);
    v[0]=a.x; v[1]=a.y; v[2]=a.z; v[3]=a.w;
    v[4]=b.x; v[5]=b.y; v[6]=b.z; v[7]=b.w;

    unsigned sel = 0;
    unsigned long long key = 0;
    for (int k = 0; k < 5; ++k) {
        float best = -3.0e38f;
        int  bidx = 0x7fffffff;
        #pragma unroll
        for (int j = 0; j < 8; ++j) {
            if (!((sel >> j) & 1u)) {
                float val = v[j];
                int   idx = base + j;
                if (val > best || (val == best && idx < bidx)) { best = val; bidx = idx; }
            }
        }
        #pragma unroll
        for (int off = 32; off > 0; off >>= 1) {
            float ov = __shfl_xor(best, off);
            int   oi = __shfl_xor(bidx, off);
            if (ov > best || (ov == best && oi < bidx)) { best = ov; bidx = oi; }
        }
        key |= (unsigned long long)(unsigned)bidx << (10 * k);
        if (bidx >= base && bidx < base + 8) sel |= 1u << (bidx - base);
    }
    if (lane == 0) keys[row] = key;
}

// ---------------------------------------------------------------------------
// Kernel 1: pair-find, OFF-DIAGONAL key duplicates only (expected ~0).
// 1024 blocks, small LDS -> high occupancy; j-keys read 2-at-a-time (b128).
// ---------------------------------------------------------------------------
__global__ __launch_bounds__(256) void pair_find_kernel(
    const unsigned long long* __restrict__ keys,
    unsigned int* __restrict__ pairs, int* __restrict__ cnt)
{
    __shared__ unsigned long long kjs[256];
    const int ibase = (blockIdx.x >> 5) * 256;
    const int jbase = (blockIdx.x & 31) * 256;
    kjs[threadIdx.x] = keys[jbase + threadIdx.x];
    __syncthreads();

    const int i = ibase + threadIdx.x;
    const unsigned long long ki = keys[i];

    #pragma unroll
    for (int batch = 0; batch < 16; ++batch) {
        unsigned long long kk[16];
        #pragma unroll
        for (int x = 0; x < 8; ++x) {
            ulonglong2 two = *reinterpret_cast<const ulonglong2*>(&kjs[batch * 16 + x * 2]);
            kk[x * 2] = two.x; kk[x * 2 + 1] = two.y;
        }
        #pragma unroll
        for (int x = 0; x < 16; ++x) {
            const int j = jbase + batch * 16 + x;
            if (kk[x] == ki && j != i) {
                int slot = atomicAdd(cnt, 1);
                if (slot < PAIR_CAP)
                    pairs[slot] = ((unsigned)i << 13) | (unsigned)j;
            }
        }
    }
}

// ---------------------------------------------------------------------------
// Kernel 2: persistent GEMM + BCE-log-product. 256 blocks (1/CU) x 512 thr
// (8 waves, 2x4). Block b: A-panel bi=b>>2 (128 rows), 16 B-tiles
// bj=(b&3)*16+t. A fragments loaded ONCE global->registers (64B-coalesced,
// no LDS). B double-buffered in LDS (2x32KB) with the verified pre-swizzled
// global_load_lds pattern. 2-phase pipeline per tile: STAGE(t+1) -> compute(t)
// -> one __syncthreads (its vmcnt(0) drain is the pipeline wait).
// Per-thread lsum accumulates log2 over all 16 tiles; one atomic per block
// into its own padded bin.
// ---------------------------------------------------------------------------
__global__ __launch_bounds__(512) void gemm_kernel(
    const unsigned short* __restrict__ bfP,
    const unsigned short* __restrict__ bfQ,
    float* __restrict__ accbins)
{
    __shared__ unsigned short Bs[2][128 * 128];   // 2 x 32 KB
    __shared__ float wsum[8];

    const int tid = threadIdx.x;
    const int b   = blockIdx.x;
    const int bi  = b >> 2;
    const int bj0 = (b & 3) * NT;
    const int row0 = bi << 7;

    const int l  = tid & 63;
    const int wv = tid >> 6;
    const int wm = wv >> 2, wn = wv & 3;     // 2 row-halves x 4 col-quarters
    const int g8 = l >> 4, q = l & 15;

    // ---- A fragments: 16 x bf16x8 = 64 VGPR, loaded once ----
    bf16x8 af[4][4];                          // [mi][ks]
    #pragma unroll
    for (int mi = 0; mi < 4; ++mi)
        #pragma unroll
        for (int ks = 0; ks < 4; ++ks)
            af[mi][ks] = *reinterpret_cast<const bf16x8*>(
                bfP + (size_t)(row0 + wm * 64 + mi * 16 + q) * C_DIM + ks * 32 + g8 * 8);

    // ---- stage helper: B tile bj into buffer buf (4 gload_lds / thread) ----
    auto STAGE = [&](int buf, int bj) {
        const int col0 = bj << 7;
        #pragma unroll
        for (int it = 0; it < 4; ++it) {
            const int g  = it * 512 + tid;   // granule (16B), [0,2048)
            const int rr = g >> 4;
            const int s  = g & 15;
            const int cw = s ^ (rr & 7);     // pre-swizzled source chunk
            const unsigned short* sB = bfQ + (size_t)(col0 + rr) * C_DIM + cw * 8;
            __builtin_amdgcn_global_load_lds(
                (const __attribute__((address_space(1))) void*)sB,
                (__attribute__((address_space(3))) void*)(&Bs[buf][g * 8]), 16, 0, 0);
        }
    };

    STAGE(0, bj0);
    __syncthreads();

    float lsum = 0.0f;
    int cur = 0;
    for (int t = 0; t < NT; ++t) {
        if (t + 1 < NT) STAGE(cur ^ 1, bj0 + t + 1);

        // ---- compute: K=128 in 4 MFMA steps; 8 ds_read_b128 / thread ----
        f32x4 accf[4][2];
        #pragma unroll
        for (int mi = 0; mi < 4; ++mi)
            #pragma unroll
            for (int ni = 0; ni < 2; ++ni) accf[mi][ni] = (f32x4){0.f, 0.f, 0.f, 0.f};

        #pragma unroll
        for (int ks = 0; ks < 4; ++ks) {
            bf16x8 bfr[2];
            #pragma unroll
            for (int ni = 0; ni < 2; ++ni) {
                const int rr = wn * 32 + ni * 16 + q;
                bfr[ni] = *reinterpret_cast<const bf16x8*>(
                    &Bs[cur][rr * 128 + ((ks * 32 + g8 * 8) ^ ((rr & 7) << 3))]);
            }
            #pragma unroll
            for (int mi = 0; mi < 4; ++mi)
                #pragma unroll
                for (int ni = 0; ni < 2; ++ni)
                    accf[mi][ni] = __builtin_amdgcn_mfma_f32_16x16x32_bf16(
                        af[mi][ks], bfr[ni], accf[mi][ni], 0, 0, 0);
        }

        // ---- epilogue: product of 32 factors, one log2, accumulate ----
        const int bj = bj0 + t;
        float pr[4] = {1.0f, 1.0f, 1.0f, 1.0f};
        if (bi == bj) {
            #pragma unroll
            for (int mi = 0; mi < 4; ++mi) {
                #pragma unroll
                for (int ni = 0; ni < 2; ++ni) {
                    const int lj = wn * 32 + ni * 16 + q;
                    #pragma unroll
                    for (int r = 0; r < 4; ++r) {
                        const float p = accf[mi][ni][r];
                        const int li = wm * 64 + mi * 16 + g8 * 4 + r;
                        pr[r] *= (li == lj) ? p : (1.0f - p);
                    }
                }
            }
        } else {
            #pragma unroll
            for (int mi = 0; mi < 4; ++mi)
                #pragma unroll
                for (int ni = 0; ni < 2; ++ni)
                    #pragma unroll
                    for (int r = 0; r < 4; ++r)
                        pr[r] *= 1.0f - accf[mi][ni][r];
        }
        lsum += __log2f((pr[0] * pr[1]) * (pr[2] * pr[3]));

        __syncthreads();                     // drains stage; guards buffer reuse
        cur ^= 1;
    }

    // ---- block reduction, one atomic into this block's own bin ----
    #pragma unroll
    for (int off = 32; off > 0; off >>= 1) lsum += __shfl_xor(lsum, off);
    if (l == 0) wsum[wv] = lsum;
    __syncthreads();
    if (tid == 0) {
        float s = 0.0f;
        #pragma unroll
        for (int w = 0; w < 8; ++w) s += wsum[w];
        atomicAdd(accbins + (b & (NBINS - 1)) * BIN_STRIDE,
                  s * 0.69314718055994531f);
    }
}

// ---------------------------------------------------------------------------
// Kernel 3 (fused): duplicate-pair correction (expected 0 pairs) + bin sum +
// finalize. Single block of 256 threads.
// ---------------------------------------------------------------------------
__global__ __launch_bounds__(256) void fix_final_kernel(
    const unsigned int* __restrict__ pairs, const int* __restrict__ cnt,
    const float* __restrict__ P, const float* __restrict__ Q,
    const float* __restrict__ accbins, float* __restrict__ out)
{
    __shared__ float wsum[4];
    __shared__ float bsum[4];
    const int lane = threadIdx.x & 63;
    const int w    = threadIdx.x >> 6;
    const int count = min(*cnt, PAIR_CAP);

    float lsum = 0.0f;
    for (int p = w; p < count; p += 4) {
        const unsigned code = pairs[p];
        const int i = code >> 13;
        const int j = code & 8191;
        float2 a = *reinterpret_cast<const float2*>(P + (size_t)i * C_DIM + lane * 2);
        float2 b = *reinterpret_cast<const float2*>(Q + (size_t)j * C_DIM + lane * 2);
        float s = fmaf(a.x, b.x, a.y * b.y);
        #pragma unroll
        for (int off = 32; off > 0; off >>= 1) s += __shfl_xor(s, off);
        if (lane == 0)
            lsum += fmaxf(__logf(s), -100.0f) - __logf(1.0f - s);
    }
    if (lane == 0) wsum[w] = lsum;

    float bv = accbins[threadIdx.x * BIN_STRIDE];
    #pragma unroll
    for (int off = 32; off > 0; off >>= 1) bv += __shfl_xor(bv, off);
    if (lane == 0) bsum[w] = bv;
    __syncthreads();

    if (threadIdx.x == 0) {
        float total = wsum[0] + wsum[1] + wsum[2] + wsum[3]
                    + bsum[0] + bsum[1] + bsum[2] + bsum[3];
        out[0] = -total / (float)((long long)B_SZ * (long long)B_SZ);
    }
}

extern "C" void kernel_launch(void* const* d_in, const int* in_sizes, int n_in,
                              void* d_out, int out_size, void* d_ws, size_t ws_size,
                              hipStream_t stream)
{
    const float* feat = (const float*)d_in[0];   // unlabel_feat     (8192, 512)
    const float* prob = (const float*)d_in[1];   // unlabel_prob     (8192, 128)
    const float* rot  = (const float*)d_in[2];   // rot_unlabel_prob (8192, 128)
    float* out = (float*)d_out;

    char* ws = (char*)d_ws;
    unsigned long long* keys = (unsigned long long*)ws;               // 64 KB
    int*   cnt     = (int*)(ws + 65536);
    float* accbins = (float*)(ws + 66560);                            // 16 KB
    unsigned short* bfP = (unsigned short*)(ws + 66560 + 16384);      // 2 MB
    unsigned short* bfQ = bfP + (size_t)B_SZ * C_DIM;                 // 2 MB
    unsigned int* pairs = (unsigned int*)(ws + 66560 + 16384 + 4 * 1024 * 1024);

    prep_kernel<<<3072, 256, 0, stream>>>(feat, prob, rot, bfP, bfQ, keys, accbins, cnt);
    pair_find_kernel<<<1024, 256, 0, stream>>>(keys, pairs, cnt);
    gemm_kernel<<<256, 512, 0, stream>>>(bfP, bfQ, accbins);
    fix_final_kernel<<<1, 256, 0, stream>>>(pairs, cnt, prob, rot, accbins, out);
}

// Round 11
// 54.645 us; speedup vs baseline: 4.6235x; 1.0686x over previous
//
#include <hip/hip_runtime.h>

#define B_SZ 8192
#define C_DIM 128
#define D_DIM 512
#define PAIR_CAP 65536
#define NBINS 256
#define BIN_STRIDE 16   // floats; 64 B -> one cache line per bin
#define NT 8            // B-tiles per persistent gemm block

typedef __bf16 bf16x8 __attribute__((ext_vector_type(8)));
typedef float  f32x4  __attribute__((ext_vector_type(4)));

// RNE float -> bf16 (inputs are finite positive probabilities; no NaN path)
__device__ inline unsigned int f2bf(float f) {
    unsigned int u = __builtin_bit_cast(unsigned int, f);
    u += 0x7FFFu + ((u >> 16) & 1u);
    return u >> 16;
}

// ---------------------------------------------------------------------------
// Kernel 0 (fused prep): blocks [0,1024) convert P,Q fp32->bf16 into ws;
// blocks [1024,3072) compute ordered top-5 keys of feat rows (one wave/row,
// 5 rounds of wave-argmax, lower-index tiebreak).
// Block 0: threads zero the 256 accumulator bins; thread 0 zeroes cnt.
// ---------------------------------------------------------------------------
__global__ __launch_bounds__(256) void prep_kernel(
    const float* __restrict__ feat,
    const float* __restrict__ P, const float* __restrict__ Q,
    unsigned short* __restrict__ bfP, unsigned short* __restrict__ bfQ,
    unsigned long long* __restrict__ keys,
    float* __restrict__ accbins, int* __restrict__ cnt)
{
    if (blockIdx.x == 0) {
        accbins[threadIdx.x * BIN_STRIDE] = 0.0f;
        if (threadIdx.x == 0) *cnt = 0;
    }

    if (blockIdx.x < 1024) {
        const int half = (B_SZ * C_DIM) / 8;          // 131072 vec8 per array
        int idx = blockIdx.x * 256 + threadIdx.x;
        const float* src = P; unsigned short* dst = bfP;
        if (idx >= half) { idx -= half; src = Q; dst = bfQ; }
        float4 a = *reinterpret_cast<const float4*>(src + (size_t)idx * 8);
        float4 b = *reinterpret_cast<const float4*>(src + (size_t)idx * 8 + 4);
        uint4 w;
        w.x = f2bf(a.x) | (f2bf(a.y) << 16);
        w.y = f2bf(a.z) | (f2bf(a.w) << 16);
        w.z = f2bf(b.x) | (f2bf(b.y) << 16);
        w.w = f2bf(b.z) | (f2bf(b.w) << 16);
        *reinterpret_cast<uint4*>(dst + (size_t)idx * 8) = w;
        return;
    }

    const int lane = threadIdx.x & 63;
    const int wv   = threadIdx.x >> 6;
    const int row  = (blockIdx.x - 1024) * 4 + wv;
    const float* f = feat + (size_t)row * D_DIM;

    const int base = lane * 8;
    float v[8];
    float4 a = *reinterpret_cast<const float4*>(f + base);
    float4 b = *reinterpret_cast<const float4*>(f + base + 4);
    v[0]=a.x; v[1]=a.y; v[2]=a.z; v[3]=a.w;
    v[4]=b.x; v[5]=b.y; v[6]=b.z; v[7]=b.w;

    unsigned sel = 0;
    unsigned long long key = 0;
    for (int k = 0; k < 5; ++k) {
        float best = -3.0e38f;
        int  bidx = 0x7fffffff;
        #pragma unroll
        for (int j = 0; j < 8; ++j) {
            if (!((sel >> j) & 1u)) {
                float val = v[j];
                int   idx = base + j;
                if (val > best || (val == best && idx < bidx)) { best = val; bidx = idx; }
            }
        }
        #pragma unroll
        for (int off = 32; off > 0; off >>= 1) {
            float ov = __shfl_xor(best, off);
            int   oi = __shfl_xor(bidx, off);
            if (ov > best || (ov == best && oi < bidx)) { best = ov; bidx = oi; }
        }
        key |= (unsigned long long)(unsigned)bidx << (10 * k);
        if (bidx >= base && bidx < base + 8) sel |= 1u << (bidx - base);
    }
    if (lane == 0) keys[row] = key;
}

// ---------------------------------------------------------------------------
// Kernel 1: pair-find, OFF-DIAGONAL key duplicates only (expected ~0).
// 1024 blocks; j-keys staged in LDS, read as uniform-address b128 broadcasts.
// ---------------------------------------------------------------------------
__global__ __launch_bounds__(256) void pair_find_kernel(
    const unsigned long long* __restrict__ keys,
    unsigned int* __restrict__ pairs, int* __restrict__ cnt)
{
    __shared__ unsigned long long kjs[256];
    const int ibase = (blockIdx.x >> 5) * 256;
    const int jbase = (blockIdx.x & 31) * 256;
    kjs[threadIdx.x] = keys[jbase + threadIdx.x];
    __syncthreads();

    const int i = ibase + threadIdx.x;
    const unsigned long long ki = keys[i];

    #pragma unroll
    for (int batch = 0; batch < 16; ++batch) {
        unsigned long long kk[16];
        #pragma unroll
        for (int x = 0; x < 8; ++x) {
            ulonglong2 two = *reinterpret_cast<const ulonglong2*>(&kjs[batch * 16 + x * 2]);
            kk[x * 2] = two.x; kk[x * 2 + 1] = two.y;
        }
        #pragma unroll
        for (int x = 0; x < 16; ++x) {
            const int j = jbase + batch * 16 + x;
            if (kk[x] == ki && j != i) {
                int slot = atomicAdd(cnt, 1);
                if (slot < PAIR_CAP)
                    pairs[slot] = ((unsigned)i << 13) | (unsigned)j;
            }
        }
    }
}

// ---------------------------------------------------------------------------
// Kernel 2: persistent GEMM + BCE-log-product.
// 512 blocks x 256 thr (4 waves 2x2, each 64x64 out) -> 2 blocks/CU.
// Block b: A-panel bi=b>>3 (128 rows) held in REGISTERS (loaded once);
// NT=8 B-tiles bj=(b&7)*8+t, B double-buffered in LDS (2x32 KB = 64 KB)
// with the verified pre-swizzled global_load_lds pattern.
// Per tile: STAGE(t+1) issued BEFORE compute(t); the barrier's vmcnt(0)
// drain is covered by compute + the co-resident sibling block (R10 ran
// 1 block/CU and ate the drain; R9 ran 2/CU but re-staged A every tile).
// ---------------------------------------------------------------------------
__global__ __launch_bounds__(256) void gemm_kernel(
    const unsigned short* __restrict__ bfP,
    const unsigned short* __restrict__ bfQ,
    float* __restrict__ accbins)
{
    __shared__ unsigned short Bs[2][128 * 128];   // 2 x 32 KB
    __shared__ float wsum[4];

    const int tid = threadIdx.x;
    const int b   = blockIdx.x;
    const int bi  = b >> 3;
    const int bj0 = (b & 7) * NT;
    const int row0 = bi << 7;

    const int l  = tid & 63;
    const int wv = tid >> 6;
    const int wm = wv >> 1, wn = wv & 1;     // 2x2 waves
    const int g8 = l >> 4, q = l & 15;

    // ---- A fragments: 16 x bf16x8 = 64 VGPR, loaded once per block ----
    bf16x8 af[4][4];                          // [mi][ks]
    #pragma unroll
    for (int mi = 0; mi < 4; ++mi)
        #pragma unroll
        for (int ks = 0; ks < 4; ++ks)
            af[mi][ks] = *reinterpret_cast<const bf16x8*>(
                bfP + (size_t)(row0 + wm * 64 + mi * 16 + q) * C_DIM + ks * 32 + g8 * 8);

    // ---- stage helper: B tile bj into buffer buf (8 gload_lds / thread) ----
    auto STAGE = [&](int buf, int bj) {
        const int col0 = bj << 7;
        #pragma unroll
        for (int it = 0; it < 8; ++it) {
            const int g  = it * 256 + tid;   // granule (16B), [0,2048)
            const int rr = g >> 4;
            const int s  = g & 15;
            const int cw = s ^ (rr & 7);     // pre-swizzled source chunk
            const unsigned short* sB = bfQ + (size_t)(col0 + rr) * C_DIM + cw * 8;
            __builtin_amdgcn_global_load_lds(
                (const __attribute__((address_space(1))) void*)sB,
                (__attribute__((address_space(3))) void*)(&Bs[buf][g * 8]), 16, 0, 0);
        }
    };

    STAGE(0, bj0);
    __syncthreads();

    float lsum = 0.0f;
    int cur = 0;
    for (int t = 0; t < NT; ++t) {
        if (t + 1 < NT) STAGE(cur ^ 1, bj0 + t + 1);

        // ---- compute: K=128 in 4 MFMA steps; 16 ds_read_b128 / thread ----
        f32x4 accf[4][4];
        #pragma unroll
        for (int mi = 0; mi < 4; ++mi)
            #pragma unroll
            for (int ni = 0; ni < 4; ++ni) accf[mi][ni] = (f32x4){0.f, 0.f, 0.f, 0.f};

        #pragma unroll
        for (int ks = 0; ks < 4; ++ks) {
            bf16x8 bfr[4];
            #pragma unroll
            for (int ni = 0; ni < 4; ++ni) {
                const int rr = wn * 64 + ni * 16 + q;
                bfr[ni] = *reinterpret_cast<const bf16x8*>(
                    &Bs[cur][rr * 128 + ((ks * 32 + g8 * 8) ^ ((rr & 7) << 3))]);
            }
            #pragma unroll
            for (int mi = 0; mi < 4; ++mi)
                #pragma unroll
                for (int ni = 0; ni < 4; ++ni)
                    accf[mi][ni] = __builtin_amdgcn_mfma_f32_16x16x32_bf16(
                        af[mi][ks], bfr[ni], accf[mi][ni], 0, 0, 0);
        }

        // ---- epilogue: product of 64 factors, one log2, accumulate ----
        const int bj = bj0 + t;
        float pr[4] = {1.0f, 1.0f, 1.0f, 1.0f};
        if (bi == bj) {
            #pragma unroll
            for (int mi = 0; mi < 4; ++mi) {
                #pragma unroll
                for (int ni = 0; ni < 4; ++ni) {
                    const int lj = wn * 64 + ni * 16 + q;
                    #pragma unroll
                    for (int r = 0; r < 4; ++r) {
                        const float p = accf[mi][ni][r];
                        const int li = wm * 64 + mi * 16 + g8 * 4 + r;
                        pr[r] *= (li == lj) ? p : (1.0f - p);
                    }
                }
            }
        } else {
            #pragma unroll
            for (int mi = 0; mi < 4; ++mi)
                #pragma unroll
                for (int ni = 0; ni < 4; ++ni)
                    #pragma unroll
                    for (int r = 0; r < 4; ++r)
                        pr[r] *= 1.0f - accf[mi][ni][r];
        }
        lsum += __log2f((pr[0] * pr[1]) * (pr[2] * pr[3]));

        __syncthreads();                     // drains stage; guards buffer reuse
        cur ^= 1;
    }

    // ---- block reduction, one atomic into this block's own bin ----
    #pragma unroll
    for (int off = 32; off > 0; off >>= 1) lsum += __shfl_xor(lsum, off);
    if (l == 0) wsum[wv] = lsum;
    __syncthreads();
    if (tid == 0) {
        float s = wsum[0] + wsum[1] + wsum[2] + wsum[3];
        atomicAdd(accbins + (b & (NBINS - 1)) * BIN_STRIDE,
                  s * 0.69314718055994531f);
    }
}

// ---------------------------------------------------------------------------
// Kernel 3 (fused): duplicate-pair correction (expected 0 pairs) + bin sum +
// finalize. Single block of 256 threads.
// ---------------------------------------------------------------------------
__global__ __launch_bounds__(256) void fix_final_kernel(
    const unsigned int* __restrict__ pairs, const int* __restrict__ cnt,
    const float* __restrict__ P, const float* __restrict__ Q,
    const float* __restrict__ accbins, float* __restrict__ out)
{
    __shared__ float wsum[4];
    __shared__ float bsum[4];
    const int lane = threadIdx.x & 63;
    const int w    = threadIdx.x >> 6;
    const int count = min(*cnt, PAIR_CAP);

    float lsum = 0.0f;
    for (int p = w; p < count; p += 4) {
        const unsigned code = pairs[p];
        const int i = code >> 13;
        const int j = code & 8191;
        float2 a = *reinterpret_cast<const float2*>(P + (size_t)i * C_DIM + lane * 2);
        float2 b = *reinterpret_cast<const float2*>(Q + (size_t)j * C_DIM + lane * 2);
        float s = fmaf(a.x, b.x, a.y * b.y);
        #pragma unroll
        for (int off = 32; off > 0; off >>= 1) s += __shfl_xor(s, off);
        if (lane == 0)
            lsum += fmaxf(__logf(s), -100.0f) - __logf(1.0f - s);
    }
    if (lane == 0) wsum[w] = lsum;

    float bv = accbins[threadIdx.x * BIN_STRIDE];
    #pragma unroll
    for (int off = 32; off > 0; off >>= 1) bv += __shfl_xor(bv, off);
    if (lane == 0) bsum[w] = bv;
    __syncthreads();

    if (threadIdx.x == 0) {
        float total = wsum[0] + wsum[1] + wsum[2] + wsum[3]
                    + bsum[0] + bsum[1] + bsum[2] + bsum[3];
        out[0] = -total / (float)((long long)B_SZ * (long long)B_SZ);
    }
}

extern "C" void kernel_launch(void* const* d_in, const int* in_sizes, int n_in,
                              void* d_out, int out_size, void* d_ws, size_t ws_size,
                              hipStream_t stream)
{
    const float* feat = (const float*)d_in[0];   // unlabel_feat     (8192, 512)
    const float* prob = (const float*)d_in[1];   // unlabel_prob     (8192, 128)
    const float* rot  = (const float*)d_in[2];   // rot_unlabel_prob (8192, 128)
    float* out = (float*)d_out;

    char* ws = (char*)d_ws;
    unsigned long long* keys = (unsigned long long*)ws;               // 64 KB
    int*   cnt     = (int*)(ws + 65536);
    float* accbins = (float*)(ws + 66560);                            // 16 KB
    unsigned short* bfP = (unsigned short*)(ws + 66560 + 16384);      // 2 MB
    unsigned short* bfQ = bfP + (size_t)B_SZ * C_DIM;                 // 2 MB
    unsigned int* pairs = (unsigned int*)(ws + 66560 + 16384 + 4 * 1024 * 1024);

    prep_kernel<<<3072, 256, 0, stream>>>(feat, prob, rot, bfP, bfQ, keys, accbins, cnt);
    pair_find_kernel<<<1024, 256, 0, stream>>>(keys, pairs, cnt);
    gemm_kernel<<<512, 256, 0, stream>>>(bfP, bfQ, accbins);
    fix_final_kernel<<<1, 256, 0, stream>>>(pairs, cnt, prob, rot, accbins, out);
}